// Round 5
// baseline (4139.265 us; speedup 1.0000x reference)
//
#include <hip/hip_runtime.h>

typedef unsigned short u16;
typedef unsigned int u32;

using bf16x8 = __attribute__((ext_vector_type(8))) __bf16;
using f32x4  = __attribute__((ext_vector_type(4))) float;
using f32x16 = __attribute__((ext_vector_type(16))) float;
using u16x8  = __attribute__((ext_vector_type(8))) u16;

#define BB 4
#define TT 4096
#define DD 2048
#define MM 16384
#define KK 2048
#define NCHUNK 16
#define CLEN 256

__device__ __forceinline__ u16 f2bf(float f) {
    u32 u = __float_as_uint(f);
    u32 r = (u + 0x7FFFu + ((u >> 16) & 1u)) >> 16;
    return (u16)r;
}

__device__ __forceinline__ void gload_lds16(const void* g, void* l) {
    __builtin_amdgcn_global_load_lds(
        (const __attribute__((address_space(1))) void*)g,
        (__attribute__((address_space(3))) void*)l, 16, 0, 0);
}

// ---------------- fp32 -> bf16 convert (8 elems/thread) ----------------
__global__ __launch_bounds__(256) void cvt_kernel(const float* __restrict__ in,
                                                  u16* __restrict__ out, int n8) {
    int i = blockIdx.x * 256 + threadIdx.x;
    if (i >= n8) return;
    const f32x4* p = (const f32x4*)in + (size_t)i * 2;
    f32x4 a = p[0], b = p[1];
    u16x8 o;
    o[0] = f2bf(a[0]); o[1] = f2bf(a[1]); o[2] = f2bf(a[2]); o[3] = f2bf(a[3]);
    o[4] = f2bf(b[0]); o[5] = f2bf(b[1]); o[6] = f2bf(b[2]); o[7] = f2bf(b[3]);
    *((u16x8*)out + i) = o;
}

// ---------------- fused dual GEMM (32x32x16, 256x256 tile) + gate epilogue ----------------
// 8 waves (2m x 4e), wave tile 128m x 64e, BK=32, 3-deep LDS pipeline (144 KB).
// Per K-step: 2 phases (ks=0,1), R3 rhythm: reads+stage | bar | lgkm0+16 MFMA | bar.
#define BMg 256
#define BNg 256
#define BKg 32
#define NT (KK / BKg)   // 64 K-steps

__global__ __launch_bounds__(512, 2) void gemm_dual32(
    const u16* __restrict__ xb, const u16* __restrict__ wib, const u16* __restrict__ wgb,
    const float* __restrict__ b_in, const float* __restrict__ b_gate,
    const float* __restrict__ lam, u32* __restrict__ pair)
{
    __shared__ u16 As[3][BMg * BKg];       // 3 x 16 KB
    __shared__ u16 Bs[3][2][BNg * BKg];    // 3 x 2 x 16 KB   (total 144 KB)

    const int tid = threadIdx.x;
    const int bid = blockIdx.x;
    const int cpx = gridDim.x >> 3;               // 512/8=64 -> bijective
    const int swz = (bid & 7) * cpx + (bid >> 3);
    const int et = swz & 7;    // 8 e-tiles
    const int mt = swz >> 3;   // 64 m-tiles
    const size_t m0 = (size_t)mt * BMg;
    const size_t e0 = (size_t)et * BNg;

    const int lane = tid & 63;
    const int wid = tid >> 6;
    const int wr = wid >> 2;    // 0..1 -> m offset wr*128
    const int wc = wid & 3;     // 0..3 -> e offset wc*64
    const int l31 = lane & 31;
    const int lhi = lane >> 5;  // 0..1

    // staging: thread tid -> LDS row tid>>2, 16B chunk tid&3; global seg = chunk ^ (row&3)
    const int srow = tid >> 2;                       // 0..127
    const int sseg = (tid & 3) ^ ((tid >> 2) & 3);
    const int skp  = sseg << 3;

    const u16* gA0 = xb  + (m0 + srow) * KK + skp;
    const u16* gA1 = gA0 + (size_t)128 * KK;
    const u16* gI0 = wib + (e0 + srow) * KK + skp;
    const u16* gI1 = gI0 + (size_t)128 * KK;
    const u16* gG0 = wgb + (e0 + srow) * KK + skp;
    const u16* gG1 = gG0 + (size_t)128 * KK;

    // read-side: chunk = (2*ks + lhi) ^ (l&3); element offset = row*32 + chunk*8
    int aoff[4][2], boff[2][2];
#pragma unroll
    for (int ks = 0; ks < 2; ks++) {
        const int ck = ((2 * ks + lhi) ^ (lane & 3)) << 3;
#pragma unroll
        for (int mi = 0; mi < 4; mi++)
            aoff[mi][ks] = (wr * 128 + mi * 32 + l31) * BKg + ck;
#pragma unroll
        for (int ni = 0; ni < 2; ni++)
            boff[ni][ks] = (wc * 64 + ni * 32 + l31) * BKg + ck;
    }

#define STAGE_A(t) do { int _b = (t) % 3; size_t _k = (size_t)(t) * BKg; \
        gload_lds16(gA0 + _k, &As[_b][tid * 8]); \
        gload_lds16(gA1 + _k, &As[_b][4096 + tid * 8]); } while (0)
#define STAGE_B(t) do { int _b = (t) % 3; size_t _k = (size_t)(t) * BKg; \
        gload_lds16(gI0 + _k, &Bs[_b][0][tid * 8]); \
        gload_lds16(gI1 + _k, &Bs[_b][0][4096 + tid * 8]); \
        gload_lds16(gG0 + _k, &Bs[_b][1][tid * 8]); \
        gload_lds16(gG1 + _k, &Bs[_b][1][4096 + tid * 8]); } while (0)

    f32x16 accI[4][2], accG[4][2];
#pragma unroll
    for (int mi = 0; mi < 4; mi++)
#pragma unroll
        for (int ni = 0; ni < 2; ni++) {
#pragma unroll
            for (int r = 0; r < 16; r++) { accI[mi][ni][r] = 0.f; accG[mi][ni][r] = 0.f; }
        }

    // prologue: stage K-steps 0 and 1
    STAGE_A(0); STAGE_B(0);
    STAGE_A(1); STAGE_B(1);
    asm volatile("s_waitcnt vmcnt(6)" ::: "memory");   // step 0 resident
    __builtin_amdgcn_s_barrier();

    bf16x8 aF[4], bI[2], bG[2];

#define READS(t, ks) do { \
        const u16* Ab = &As[(t) % 3][0]; \
        const u16* BiB = &Bs[(t) % 3][0][0]; \
        const u16* BgB = &Bs[(t) % 3][1][0]; \
        _Pragma("unroll") for (int mi = 0; mi < 4; mi++) aF[mi] = *(const bf16x8*)&Ab[aoff[mi][ks]]; \
        _Pragma("unroll") for (int ni = 0; ni < 2; ni++) { \
            bI[ni] = *(const bf16x8*)&BiB[boff[ni][ks]]; \
            bG[ni] = *(const bf16x8*)&BgB[boff[ni][ks]]; } \
    } while (0)
#define BURST() do { \
        asm volatile("s_waitcnt lgkmcnt(0)" ::: "memory"); \
        __builtin_amdgcn_sched_barrier(0); \
        __builtin_amdgcn_s_setprio(1); \
        _Pragma("unroll") for (int mi = 0; mi < 4; mi++) \
        _Pragma("unroll") for (int ni = 0; ni < 2; ni++) { \
            accI[mi][ni] = __builtin_amdgcn_mfma_f32_32x32x16_bf16(aF[mi], bI[ni], accI[mi][ni], 0, 0, 0); \
            accG[mi][ni] = __builtin_amdgcn_mfma_f32_32x32x16_bf16(aF[mi], bG[ni], accG[mi][ni], 0, 0, 0); } \
        __builtin_amdgcn_s_setprio(0); \
    } while (0)

#pragma unroll 3
    for (int t = 0; t < NT; ++t) {
        // phase 0 (ks=0)
        READS(t, 0);
        if (t < NT - 2) STAGE_A(t + 2);
        __builtin_amdgcn_s_barrier();
        BURST();
        __builtin_amdgcn_s_barrier();
        // phase 1 (ks=1)
        READS(t, 1);
        if (t < NT - 2) STAGE_B(t + 2);
        __builtin_amdgcn_s_barrier();
        BURST();
        if (t < NT - 2)       asm volatile("s_waitcnt vmcnt(6)" ::: "memory");
        else if (t == NT - 2) asm volatile("s_waitcnt vmcnt(0)" ::: "memory");
        __builtin_amdgcn_s_barrier();
    }

    // ---- epilogue ----
    float spl[2], biv[2], bgv[2];
    size_t ecol[2];
#pragma unroll
    for (int ni = 0; ni < 2; ni++) {
        size_t e = e0 + wc * 64 + ni * 32 + l31;
        ecol[ni] = e;
        spl[ni] = 8.0f * log1pf(__expf(lam[e]));
        biv[ni] = b_in[e];
        bgv[ni] = b_gate[e];
    }
#pragma unroll
    for (int mi = 0; mi < 4; mi++) {
#pragma unroll
        for (int r = 0; r < 16; r++) {
            size_t m = m0 + wr * 128 + mi * 32 + (r & 3) + 8 * (r >> 2) + 4 * lhi;
#pragma unroll
            for (int ni = 0; ni < 2; ni++) {
                size_t e = ecol[ni];
                float ig = accI[mi][ni][r] + biv[ni];
                float rg = accG[mi][ni][r] + bgv[ni];
                float sigr = 1.f / (1.f + __expf(-rg));
                float g = spl[ni] * sigr;
                float beta = sqrtf(1.f - __expf(-2.f * g) + 1e-6f);
                float xv = __uint_as_float((u32)xb[m * KK + e] << 16);  // L2-hot bf16 x
                float xbeta = beta * (1.f / (1.f + __expf(-ig))) * xv;
                u32 pk = (u32)f2bf(g) | (((u32)f2bf(xbeta)) << 16);
                pair[m * DD + e] = pk;
            }
        }
    }
#undef STAGE_A
#undef STAGE_B
#undef READS
#undef BURST
}

// ---------------- chunked scan ----------------
// pair layout [B,T,D]: low16 = bf16(g), high16 = bf16(xbeta); alpha = exp(-g)
__global__ __launch_bounds__(256) void scanA(const u32* __restrict__ pair,
                                             float* __restrict__ aggG,
                                             float* __restrict__ aggB) {
    int gid = blockIdx.x * 256 + threadIdx.x;   // 131072
    int e = gid & (DD - 1);
    int rest = gid >> 11;     // 0..63
    int b = rest & 3;
    int c = rest >> 2;        // 0..15
    const u32* p = pair + ((size_t)(b * TT + c * CLEN)) * DD + e;
    float gsum = 0.f, h = 0.f;
#pragma unroll 4
    for (int t = 0; t < CLEN; ++t) {
        u32 v = *p; p += DD;
        float gf = __uint_as_float(v << 16);
        float xbv = __uint_as_float(v & 0xFFFF0000u);
        gsum += gf;
        h = fmaf(__expf(-gf), h, xbv);
    }
    int idx = ((b * NCHUNK + c) << 11) | e;
    aggG[idx] = gsum;
    aggB[idx] = h;
}

__global__ __launch_bounds__(256) void scanB(const float* __restrict__ aggG,
                                             const float* __restrict__ aggB,
                                             float* __restrict__ carry) {
    int gid = blockIdx.x * 256 + threadIdx.x;   // 8192
    int e = gid & (DD - 1);
    int b = gid >> 11;
    float h = 0.f;
#pragma unroll
    for (int c = 0; c < NCHUNK; ++c) {
        int idx = ((b * NCHUNK + c) << 11) | e;
        carry[idx] = h;
        h = fmaf(__expf(-aggG[idx]), h, aggB[idx]);
    }
}

__global__ __launch_bounds__(256) void scanC(const u32* __restrict__ pair,
                                             const float* __restrict__ carry,
                                             float* __restrict__ out) {
    int gid = blockIdx.x * 256 + threadIdx.x;   // 131072
    int e = gid & (DD - 1);
    int rest = gid >> 11;
    int b = rest & 3;
    int c = rest >> 2;
    const u32* p = pair + ((size_t)(b * TT + c * CLEN)) * DD + e;
    float* o = out + ((size_t)(b * TT + c * CLEN)) * DD + e;
    float h = carry[((b * NCHUNK + c) << 11) | e];
#pragma unroll 4
    for (int t = 0; t < CLEN; ++t) {
        u32 v = *p; p += DD;
        float gf = __uint_as_float(v << 16);
        float xbv = __uint_as_float(v & 0xFFFF0000u);
        h = fmaf(__expf(-gf), h, xbv);
        *o = h; o += DD;
    }
}

extern "C" void kernel_launch(void* const* d_in, const int* in_sizes, int n_in,
                              void* d_out, int out_size, void* d_ws, size_t ws_size,
                              hipStream_t stream) {
    const float* x      = (const float*)d_in[0];
    const float* W_in   = (const float*)d_in[1];
    const float* b_in   = (const float*)d_in[2];
    const float* W_gate = (const float*)d_in[3];
    const float* b_gate = (const float*)d_in[4];
    const float* lam    = (const float*)d_in[5];
    float* out = (float*)d_out;

    char* ws = (char*)d_ws;
    u16* xb   = (u16*)(ws);                  // 67,108,864 B
    u16* wib  = (u16*)(ws + 67108864);       //  8,388,608 B
    u16* wgb  = (u16*)(ws + 75497472);       //  8,388,608 B
    u32* pair = (u32*)(ws + 83886080);       // 134,217,728 B
    float* aggG  = (float*)(ws + 218103808); // 524,288 B
    float* aggB  = (float*)(ws + 218628096); // 524,288 B
    float* carry = (float*)(ws + 219152384); // 524,288 B

    cvt_kernel<<<16384, 256, 0, stream>>>(x, xb, MM * KK / 8);
    cvt_kernel<<<2048, 256, 0, stream>>>(W_in, wib, DD * KK / 8);
    cvt_kernel<<<2048, 256, 0, stream>>>(W_gate, wgb, DD * KK / 8);
    gemm_dual32<<<(MM / BMg) * (DD / BNg), 512, 0, stream>>>(xb, wib, wgb, b_in, b_gate, lam, pair);
    scanA<<<BB * DD * NCHUNK / 256, 256, 0, stream>>>(pair, aggG, aggB);
    scanB<<<BB * DD / 256, 256, 0, stream>>>(aggG, aggB, carry);
    scanC<<<BB * DD * NCHUNK / 256, 256, 0, stream>>>(pair, carry, out);
}

// Round 6
// 607.207 us; speedup vs baseline: 6.8169x; 6.8169x over previous
//
#include <hip/hip_runtime.h>

typedef unsigned short u16;
typedef unsigned int u32;

using bf16x8 = __attribute__((ext_vector_type(8))) __bf16;
using f32x4  = __attribute__((ext_vector_type(4))) float;
using u16x8  = __attribute__((ext_vector_type(8))) u16;

#define BB 4
#define TT 4096
#define DD 2048
#define MM 16384
#define KK 2048
#define NN 4096          // concat-N
#define NCHUNK 16
#define CLEN 256

__device__ __forceinline__ u16 f2bf(float f) {
    u32 u = __float_as_uint(f);
    u32 r = (u + 0x7FFFu + ((u >> 16) & 1u)) >> 16;
    return (u16)r;
}

__device__ __forceinline__ void gload_lds16(const void* g, void* l) {
    __builtin_amdgcn_global_load_lds(
        (const __attribute__((address_space(1))) void*)g,
        (__attribute__((address_space(3))) void*)l, 16, 0, 0);
}

// ---------------- fp32 -> bf16 convert (8 elems/thread) ----------------
__global__ __launch_bounds__(256) void cvt_kernel(const float* __restrict__ in,
                                                  u16* __restrict__ out, int n8) {
    int i = blockIdx.x * 256 + threadIdx.x;
    if (i >= n8) return;
    const f32x4* p = (const f32x4*)in + (size_t)i * 2;
    f32x4 a = p[0], b = p[1];
    u16x8 o;
    o[0] = f2bf(a[0]); o[1] = f2bf(a[1]); o[2] = f2bf(a[2]); o[3] = f2bf(a[3]);
    o[4] = f2bf(b[0]); o[5] = f2bf(b[1]); o[6] = f2bf(b[2]); o[7] = f2bf(b[3]);
    *((u16x8*)out + i) = o;
}

// W convert with channel interleave: out row 2e+gate = in row e
__global__ __launch_bounds__(256) void cvtw_kernel(const float* __restrict__ in,
                                                   u16* __restrict__ out, int gate) {
    int i = blockIdx.x * 256 + threadIdx.x;        // 2048*2048/8 threads
    int row = i >> 8;                              // source row
    int col8 = i & 255;                            // 8-elem group in row
    const f32x4* p = (const f32x4*)in + (size_t)i * 2;
    f32x4 a = p[0], b = p[1];
    u16x8 o;
    o[0] = f2bf(a[0]); o[1] = f2bf(a[1]); o[2] = f2bf(a[2]); o[3] = f2bf(a[3]);
    o[4] = f2bf(b[0]); o[5] = f2bf(b[1]); o[6] = f2bf(b[2]); o[7] = f2bf(b[3]);
    size_t oidx = (((size_t)row * 2 + gate) << 11) + (size_t)col8 * 8;
    *(u16x8*)(out + oidx) = o;
}

// ---------------- concat-N GEMM (256x256 tile, BK=64) + paired-gate epilogue ----------------
// C[M=16384, N=4096] = Xb @ Wc^T. Wc rows interleaved: 2e=W_in[e], 2e+1=W_gate[e].
// 8 waves (2m x 4n), wave tile 128m x 64n, acc = 32 f32x4 = 128 VGPR.
// 2-deep LDS dbuf (128 KB), 1 barrier + 1 vmcnt(0) per K-tile, reg-dbuf'd frag pipeline.
#define BKc 64
#define NT (KK / BKc)   // 32 K-tiles

#define MF(a_, b_, c_) __builtin_amdgcn_mfma_f32_16x16x32_bf16(a_, b_, c_, 0, 0, 0)
#define MFMA8(Aa_, Ab_, B0_, B1_, B2_, B3_, ma_, mb_) do { \
    acc[ma_][0] = MF(Aa_, B0_, acc[ma_][0]); \
    acc[ma_][1] = MF(Aa_, B1_, acc[ma_][1]); \
    acc[ma_][2] = MF(Aa_, B2_, acc[ma_][2]); \
    acc[ma_][3] = MF(Aa_, B3_, acc[ma_][3]); \
    acc[mb_][0] = MF(Ab_, B0_, acc[mb_][0]); \
    acc[mb_][1] = MF(Ab_, B1_, acc[mb_][1]); \
    acc[mb_][2] = MF(Ab_, B2_, acc[mb_][2]); \
    acc[mb_][3] = MF(Ab_, B3_, acc[mb_][3]); \
} while (0)

__global__ __launch_bounds__(512, 2) void gemm_cat(
    const u16* __restrict__ xb, const u16* __restrict__ wc,
    const float* __restrict__ b_in, const float* __restrict__ b_gate,
    const float* __restrict__ lam, u32* __restrict__ pair)
{
    __shared__ u16 As[2][256 * BKc];   // 2 x 32 KB
    __shared__ u16 Bs[2][256 * BKc];   // 2 x 32 KB  (128 KB total)

    const int tid = threadIdx.x;
    const int bid = blockIdx.x;
    const int cpx = gridDim.x >> 3;               // 1024/8 = 128 -> bijective
    const int swz = (bid & 7) * cpx + (bid >> 3);
    const int nt = swz & 15;    // 16 n-tiles
    const int mt = swz >> 4;    // 64 m-tiles
    const size_t m0 = (size_t)mt * 256;
    const size_t n0 = (size_t)nt * 256;

    const int lane = tid & 63;
    const int wid = tid >> 6;
    const int wr = wid >> 2;    // 0..1 -> m offset wr*128
    const int wcv = (wid & 3) * 64;   // n offset
    const int r15 = lane & 15;
    const int s4 = lane >> 4;   // 0..3

    // staging: chunk c = i*512+tid -> LDS row c>>3, seg c&7; global seg' = seg ^ (row&7)
    const u16* gA[4];
    const u16* gB[4];
#pragma unroll
    for (int i = 0; i < 4; i++) {
        int c = i * 512 + tid;
        int r = c >> 3, seg = c & 7;
        int segp = seg ^ (r & 7);
        gA[i] = xb + (m0 + r) * (size_t)KK + segp * 8;
        gB[i] = wc + (n0 + r) * (size_t)KK + segp * 8;
    }

#define STAGE(t) do { int _b = (t) & 1; size_t _k = (size_t)(t) * BKc; \
        _Pragma("unroll") for (int i = 0; i < 4; i++) \
            gload_lds16(gA[i] + _k, &As[_b][(i * 512 + tid) * 8]); \
        _Pragma("unroll") for (int i = 0; i < 4; i++) \
            gload_lds16(gB[i] + _k, &Bs[_b][(i * 512 + tid) * 8]); } while (0)

    // read offsets (elements): row base + swizzled k-chunk
    int kx[2];
#pragma unroll
    for (int ks = 0; ks < 2; ks++) kx[ks] = (((ks * 4 + s4) ^ (r15 & 7)) << 3);
    int arow[8], brow[4];
#pragma unroll
    for (int mi = 0; mi < 8; mi++) arow[mi] = (wr * 128 + mi * 16 + r15) << 6;
#pragma unroll
    for (int ni = 0; ni < 4; ni++) brow[ni] = (wcv + ni * 16 + r15) << 6;

#define RA(mi_, ks_) (*(const bf16x8*)&Ab[arow[mi_] + kx[ks_]])
#define RB(ni_, ks_) (*(const bf16x8*)&Bb[brow[ni_] + kx[ks_]])

    f32x4 acc[8][4];
#pragma unroll
    for (int i = 0; i < 8; i++)
#pragma unroll
        for (int j = 0; j < 4; j++) acc[i][j] = (f32x4){0.f, 0.f, 0.f, 0.f};

    STAGE(0);

#define ITER(t_, bi_) do { \
        asm volatile("s_waitcnt vmcnt(0)" ::: "memory"); \
        __builtin_amdgcn_s_barrier(); \
        if ((t_) + 1 < NT) STAGE((t_) + 1); \
        const u16* Ab = &As[bi_][0]; \
        const u16* Bb = &Bs[bi_][0]; \
        bf16x8 b0, b1, b2, b3, c0, c1, c2, c3, x0, x1, y0, y1; \
        b0 = RB(0, 0); b1 = RB(1, 0); b2 = RB(2, 0); b3 = RB(3, 0); \
        x0 = RA(0, 0); x1 = RA(1, 0); \
        y0 = RA(2, 0); y1 = RA(3, 0);  MFMA8(x0, x1, b0, b1, b2, b3, 0, 1); \
        x0 = RA(4, 0); x1 = RA(5, 0);  MFMA8(y0, y1, b0, b1, b2, b3, 2, 3); \
        y0 = RA(6, 0); y1 = RA(7, 0);  MFMA8(x0, x1, b0, b1, b2, b3, 4, 5); \
        c0 = RB(0, 1); c1 = RB(1, 1); c2 = RB(2, 1); c3 = RB(3, 1); \
        x0 = RA(0, 1); x1 = RA(1, 1);  MFMA8(y0, y1, b0, b1, b2, b3, 6, 7); \
        y0 = RA(2, 1); y1 = RA(3, 1);  MFMA8(x0, x1, c0, c1, c2, c3, 0, 1); \
        x0 = RA(4, 1); x1 = RA(5, 1);  MFMA8(y0, y1, c0, c1, c2, c3, 2, 3); \
        y0 = RA(6, 1); y1 = RA(7, 1);  MFMA8(x0, x1, c0, c1, c2, c3, 4, 5); \
                                       MFMA8(y0, y1, c0, c1, c2, c3, 6, 7); \
    } while (0)

    for (int tt = 0; tt < NT; tt += 2) {
        ITER(tt, 0);
        ITER(tt + 1, 1);
    }

    // ---- epilogue: paired-gate math via shfl_xor(1) ----
    // col n = n0 + wcv + ni*16 + r15; channel = n>>1; gate = r15&1 (0 = in, 1 = gate)
    const int gate = r15 & 1;
#pragma unroll
    for (int ni = 0; ni < 4; ni++) {
        size_t n = n0 + wcv + ni * 16 + r15;
        size_t ch = n >> 1;
        float spl = 8.0f * log1pf(__expf(lam[ch]));
        float biv = b_in[ch];
        float bgv = b_gate[ch];
#pragma unroll
        for (int mi = 0; mi < 8; mi++) {
#pragma unroll
            for (int r = 0; r < 4; r++) {
                float own = acc[mi][ni][r];
                float oth = __shfl_xor(own, 1, 64);
                float ig = (gate ? oth : own) + biv;
                float rg = (gate ? own : oth) + bgv;
                float sigr = 1.f / (1.f + __expf(-rg));
                float g = spl * sigr;
                float beta = sqrtf(1.f - __expf(-2.f * g) + 1e-6f);
                size_t m = m0 + wr * 128 + mi * 16 + s4 * 4 + r;
                float xv = __uint_as_float((u32)xb[m * KK + ch] << 16);
                float xbeta = beta * (1.f / (1.f + __expf(-ig))) * xv;
                u32 pk = (u32)f2bf(g) | (((u32)f2bf(xbeta)) << 16);
                if (!gate) pair[m * DD + ch] = pk;
            }
        }
    }
#undef STAGE
#undef RA
#undef RB
#undef ITER
}

// ---------------- chunked scan ----------------
// pair layout [B,T,D]: low16 = bf16(g), high16 = bf16(xbeta); alpha = exp(-g)
__global__ __launch_bounds__(256) void scanA(const u32* __restrict__ pair,
                                             float* __restrict__ aggG,
                                             float* __restrict__ aggB) {
    int gid = blockIdx.x * 256 + threadIdx.x;   // 131072
    int e = gid & (DD - 1);
    int rest = gid >> 11;     // 0..63
    int b = rest & 3;
    int c = rest >> 2;        // 0..15
    const u32* p = pair + ((size_t)(b * TT + c * CLEN)) * DD + e;
    float gsum = 0.f, h = 0.f;
#pragma unroll 4
    for (int t = 0; t < CLEN; ++t) {
        u32 v = *p; p += DD;
        float gf = __uint_as_float(v << 16);
        float xbv = __uint_as_float(v & 0xFFFF0000u);
        gsum += gf;
        h = fmaf(__expf(-gf), h, xbv);
    }
    int idx = ((b * NCHUNK + c) << 11) | e;
    aggG[idx] = gsum;
    aggB[idx] = h;
}

__global__ __launch_bounds__(256) void scanB(const float* __restrict__ aggG,
                                             const float* __restrict__ aggB,
                                             float* __restrict__ carry) {
    int gid = blockIdx.x * 256 + threadIdx.x;   // 8192
    int e = gid & (DD - 1);
    int b = gid >> 11;
    float h = 0.f;
#pragma unroll
    for (int c = 0; c < NCHUNK; ++c) {
        int idx = ((b * NCHUNK + c) << 11) | e;
        carry[idx] = h;
        h = fmaf(__expf(-aggG[idx]), h, aggB[idx]);
    }
}

__global__ __launch_bounds__(256) void scanC(const u32* __restrict__ pair,
                                             const float* __restrict__ carry,
                                             float* __restrict__ out) {
    int gid = blockIdx.x * 256 + threadIdx.x;   // 131072
    int e = gid & (DD - 1);
    int rest = gid >> 11;
    int b = rest & 3;
    int c = rest >> 2;
    const u32* p = pair + ((size_t)(b * TT + c * CLEN)) * DD + e;
    float* o = out + ((size_t)(b * TT + c * CLEN)) * DD + e;
    float h = carry[((b * NCHUNK + c) << 11) | e];
#pragma unroll 4
    for (int t = 0; t < CLEN; ++t) {
        u32 v = *p; p += DD;
        float gf = __uint_as_float(v << 16);
        float xbv = __uint_as_float(v & 0xFFFF0000u);
        h = fmaf(__expf(-gf), h, xbv);
        *o = h; o += DD;
    }
}

extern "C" void kernel_launch(void* const* d_in, const int* in_sizes, int n_in,
                              void* d_out, int out_size, void* d_ws, size_t ws_size,
                              hipStream_t stream) {
    const float* x      = (const float*)d_in[0];
    const float* W_in   = (const float*)d_in[1];
    const float* b_in   = (const float*)d_in[2];
    const float* W_gate = (const float*)d_in[3];
    const float* b_gate = (const float*)d_in[4];
    const float* lam    = (const float*)d_in[5];
    float* out = (float*)d_out;

    char* ws = (char*)d_ws;
    u16* xb   = (u16*)(ws);                  // 67,108,864 B
    u16* wc   = (u16*)(ws + 67108864);       // 16,777,216 B (interleaved [4096][2048] bf16)
    u32* pair = (u32*)(ws + 83886080);       // 134,217,728 B
    float* aggG  = (float*)(ws + 218103808); // 524,288 B
    float* aggB  = (float*)(ws + 218628096); // 524,288 B
    float* carry = (float*)(ws + 219152384); // 524,288 B

    cvt_kernel<<<16384, 256, 0, stream>>>(x, xb, MM * KK / 8);
    cvtw_kernel<<<2048, 256, 0, stream>>>(W_in, wc, 0);
    cvtw_kernel<<<2048, 256, 0, stream>>>(W_gate, wc, 1);
    gemm_cat<<<(MM / 256) * (NN / 256), 512, 0, stream>>>(xb, wc, b_in, b_gate, lam, pair);
    scanA<<<BB * DD * NCHUNK / 256, 256, 0, stream>>>(pair, aggG, aggB);
    scanB<<<BB * DD / 256, 256, 0, stream>>>(aggG, aggB, carry);
    scanC<<<BB * DD * NCHUNK / 256, 256, 0, stream>>>(pair, carry, out);
}

// Round 7
// 439.408 us; speedup vs baseline: 9.4201x; 1.3819x over previous
//
#include <hip/hip_runtime.h>

typedef unsigned short u16;
typedef unsigned int u32;

using bf16x8 = __attribute__((ext_vector_type(8))) __bf16;
using f32x4  = __attribute__((ext_vector_type(4))) float;
using u16x8  = __attribute__((ext_vector_type(8))) u16;

#define BB 4
#define TT 4096
#define DD 2048
#define MM 16384
#define KK 2048
#define NCHUNK 16
#define CLEN 256

__device__ __forceinline__ u16 f2bf(float f) {
    u32 u = __float_as_uint(f);
    u32 r = (u + 0x7FFFu + ((u >> 16) & 1u)) >> 16;
    return (u16)r;
}

__device__ __forceinline__ void gload_lds16(const void* g, void* l) {
    __builtin_amdgcn_global_load_lds(
        (const __attribute__((address_space(1))) void*)g,
        (__attribute__((address_space(3))) void*)l, 16, 0, 0);
}

// ---------------- fp32 -> bf16 convert (8 elems/thread) ----------------
__global__ __launch_bounds__(256) void cvt_kernel(const float* __restrict__ in,
                                                  u16* __restrict__ out, int n8) {
    int i = blockIdx.x * 256 + threadIdx.x;
    if (i >= n8) return;
    const f32x4* p = (const f32x4*)in + (size_t)i * 2;
    f32x4 a = p[0], b = p[1];
    u16x8 o;
    o[0] = f2bf(a[0]); o[1] = f2bf(a[1]); o[2] = f2bf(a[2]); o[3] = f2bf(a[3]);
    o[4] = f2bf(b[0]); o[5] = f2bf(b[1]); o[6] = f2bf(b[2]); o[7] = f2bf(b[3]);
    *((u16x8*)out + i) = o;
}

// ---------------- fused dual GEMM + gate epilogue ----------------
// Tile 256(M) x 128(e), BK=32, 8 waves (2M x 4N), 4-deep LDS ring.
// Cross-step fragment prefetch: step t's MFMAs consume frags read during step
// t-1; 1 barrier/step; counted lgkmcnt(4)/(8); vmcnt(4) (tile t+1 resident a
// step early so next-step frag reads are legal).
#define BMg 256
#define BNg 128
#define BKg 32
#define NT (KK / BKg)   // 64 K-steps

__global__ __launch_bounds__(512, 2) void gemm_dual8(
    const u16* __restrict__ xb, const u16* __restrict__ wib, const u16* __restrict__ wgb,
    const float* __restrict__ b_in, const float* __restrict__ b_gate,
    const float* __restrict__ lam, u32* __restrict__ pair)
{
    __shared__ u16 As[4][BMg * BKg];       // 4 x 16 KB
    __shared__ u16 Bs[4][2][BNg * BKg];    // 4 x 2 x 8 KB   (total 128 KB)

    const int tid = threadIdx.x;
    const int bid = blockIdx.x;
    const int cpx = gridDim.x >> 3;               // 1024 % 8 == 0 -> bijective
    const int swz = (bid & 7) * cpx + (bid >> 3);
    const int et = swz & 15;
    const int mt = swz >> 4;
    const size_t m0 = (size_t)mt * BMg;
    const size_t e0 = (size_t)et * BNg;

    const int lane = tid & 63;
    const int wid = tid >> 6;
    const int wr = wid >> 2;    // 0..1 -> m offset wr*128
    const int wc = wid & 3;     // 0..3 -> e offset wc*32
    const int r15 = lane & 15;
    const int s4 = lane >> 4;   // 0..3 k-segment

    // staging map (swizzle on the GLOBAL side; LDS dest stays linear)
    const int srow = tid >> 2;                       // 0..127
    const int sseg = (tid & 3) ^ ((tid >> 3) & 3);   // swizzled 16B segment
    const int skp  = sseg << 3;

    // read-side swizzled k offset (involution of the staging swizzle)
    const int koff = ((s4 ^ ((r15 >> 1) & 3)) << 3);

    const u16* gA0 = xb  + (m0 + srow) * KK + skp;
    const u16* gA1 = gA0 + (size_t)128 * KK;
    const u16* gI  = wib + (e0 + srow) * KK + skp;
    const u16* gG  = wgb + (e0 + srow) * KK + skp;

    int aoff[8], boff[2];
#pragma unroll
    for (int q = 0; q < 8; q++) aoff[q] = (wr * 128 + q * 16 + r15) * BKg + koff;
#pragma unroll
    for (int ni = 0; ni < 2; ni++) boff[ni] = (wc * 32 + ni * 16 + r15) * BKg + koff;

#define STAGE_A(t) do { int _b = (t) & 3; size_t _k = (size_t)(t) * BKg; \
        gload_lds16(gA0 + _k, &As[_b][tid * 8]); \
        gload_lds16(gA1 + _k, &As[_b][4096 + tid * 8]); } while (0)
#define STAGE_B(t) do { int _b = (t) & 3; size_t _k = (size_t)(t) * BKg; \
        gload_lds16(gI + _k, &Bs[_b][0][tid * 8]); \
        gload_lds16(gG + _k, &Bs[_b][1][tid * 8]); } while (0)

    f32x4 accI[8][2], accG[8][2];
#pragma unroll
    for (int i = 0; i < 8; i++)
#pragma unroll
        for (int j = 0; j < 2; j++) {
            accI[i][j] = (f32x4){0.f, 0.f, 0.f, 0.f};
            accG[i][j] = (f32x4){0.f, 0.f, 0.f, 0.f};
        }

    // prologue: stage K-steps 0,1,2; tiles 0 AND 1 must be resident (step 0
    // prefetches tile 1's frags), so drain to vmcnt(4) (leave tile 2's 4 loads)
    STAGE_A(0); STAGE_B(0);
    STAGE_A(1); STAGE_B(1);
    STAGE_A(2); STAGE_B(2);
    asm volatile("s_waitcnt vmcnt(4)" ::: "memory");
    __builtin_amdgcn_s_barrier();

    bf16x8 aq0[4], aq1[4], bIA[2], bGA[2], bIB[2], bGB[2];

    // preload quad0(0) frags + B(0): 8 ds_reads, drained by step 0's lgkmcnt(4)
    {
        const u16* Ab = &As[0][0];
        const u16* Bi = &Bs[0][0][0];
        const u16* Bg = &Bs[0][1][0];
#pragma unroll
        for (int q = 0; q < 4; q++) aq0[q] = *(const bf16x8*)&Ab[aoff[q]];
#pragma unroll
        for (int ni = 0; ni < 2; ni++) {
            bIA[ni] = *(const bf16x8*)&Bi[boff[ni]];
            bGA[ni] = *(const bf16x8*)&Bg[boff[ni]];
        }
    }

    // STEP(t): consume frags read last step (quad0: aq0, B cur); read ahead.
#define STEP(t, bIc, bGc, bIn, bGn) do { \
        /* early reads: Aq1(t)  [4 ds_read] */ \
        { const u16* Ab = &As[(t) & 3][0]; \
          _Pragma("unroll") for (int q = 0; q < 4; q++) \
              aq1[q] = *(const bf16x8*)&Ab[aoff[q + 4]]; } \
        if ((t) < NT - 3) STAGE_A((t) + 3); \
        asm volatile("s_waitcnt lgkmcnt(4)" ::: "memory"); /* prev late-8 done */ \
        __builtin_amdgcn_sched_barrier(0); \
        __builtin_amdgcn_s_setprio(1); \
        _Pragma("unroll") for (int q = 0; q < 4; q++) \
        _Pragma("unroll") for (int ni = 0; ni < 2; ni++) { \
            accI[q][ni] = __builtin_amdgcn_mfma_f32_16x16x32_bf16(aq0[q], bIc[ni], accI[q][ni], 0, 0, 0); \
            accG[q][ni] = __builtin_amdgcn_mfma_f32_16x16x32_bf16(aq0[q], bGc[ni], accG[q][ni], 0, 0, 0); } \
        __builtin_amdgcn_s_setprio(0); \
        /* late reads: Aq0(t+1) + B(t+1)  [8 ds_read] (t=NT-1 reads stale slot; unused) */ \
        { const u16* Ab2 = &As[((t) + 1) & 3][0]; \
          const u16* Bi2 = &Bs[((t) + 1) & 3][0][0]; \
          const u16* Bg2 = &Bs[((t) + 1) & 3][1][0]; \
          _Pragma("unroll") for (int q = 0; q < 4; q++) \
              aq0[q] = *(const bf16x8*)&Ab2[aoff[q]]; \
          _Pragma("unroll") for (int ni = 0; ni < 2; ni++) { \
              bIn[ni] = *(const bf16x8*)&Bi2[boff[ni]]; \
              bGn[ni] = *(const bf16x8*)&Bg2[boff[ni]]; } } \
        if ((t) < NT - 3) STAGE_B((t) + 3); \
        asm volatile("s_waitcnt lgkmcnt(8)" ::: "memory"); /* early-4 done */ \
        __builtin_amdgcn_sched_barrier(0); \
        __builtin_amdgcn_s_setprio(1); \
        _Pragma("unroll") for (int q = 0; q < 4; q++) \
        _Pragma("unroll") for (int ni = 0; ni < 2; ni++) { \
            accI[q + 4][ni] = __builtin_amdgcn_mfma_f32_16x16x32_bf16(aq1[q], bIc[ni], accI[q + 4][ni], 0, 0, 0); \
            accG[q + 4][ni] = __builtin_amdgcn_mfma_f32_16x16x32_bf16(aq1[q], bGc[ni], accG[q + 4][ni], 0, 0, 0); } \
        __builtin_amdgcn_s_setprio(0); \
        if ((t) < NT - 3) asm volatile("s_waitcnt vmcnt(4)" ::: "memory"); \
        else              asm volatile("s_waitcnt vmcnt(0)" ::: "memory"); \
        __builtin_amdgcn_s_barrier(); \
    } while (0)

#pragma unroll 2
    for (int t = 0; t < NT; t += 2) {
        STEP(t,     bIA, bGA, bIB, bGB);
        STEP(t + 1, bIB, bGB, bIA, bGA);
    }

    // ---- epilogue ----
    float spl[2], biv[2], bgv[2];
    size_t ecol[2];
#pragma unroll
    for (int ni = 0; ni < 2; ni++) {
        size_t e = e0 + wc * 32 + ni * 16 + r15;
        ecol[ni] = e;
        spl[ni] = 8.0f * log1pf(__expf(lam[e]));
        biv[ni] = b_in[e];
        bgv[ni] = b_gate[e];
    }
    const int rbase = s4 * 4;
#pragma unroll
    for (int mi = 0; mi < 8; mi++) {
#pragma unroll
        for (int r = 0; r < 4; r++) {
            size_t m = m0 + wr * 128 + mi * 16 + rbase + r;
#pragma unroll
            for (int ni = 0; ni < 2; ni++) {
                size_t e = ecol[ni];
                float ig = accI[mi][ni][r] + biv[ni];
                float rg = accG[mi][ni][r] + bgv[ni];
                float sigr = 1.f / (1.f + __expf(-rg));
                float g = spl[ni] * sigr;
                float beta = sqrtf(1.f - __expf(-2.f * g) + 1e-6f);
                float xv = __uint_as_float((u32)xb[m * KK + e] << 16);  // L2-hot bf16 x
                float xbeta = beta * (1.f / (1.f + __expf(-ig))) * xv;
                u32 pk = (u32)f2bf(g) | (((u32)f2bf(xbeta)) << 16);
                pair[m * DD + e] = pk;
            }
        }
    }
#undef STAGE_A
#undef STAGE_B
#undef STEP
}

// ---------------- chunked scan ----------------
// pair layout [B,T,D]: low16 = bf16(g), high16 = bf16(xbeta); alpha = exp(-g)
__global__ __launch_bounds__(256) void scanA(const u32* __restrict__ pair,
                                             float* __restrict__ aggG,
                                             float* __restrict__ aggB) {
    int gid = blockIdx.x * 256 + threadIdx.x;   // 131072
    int e = gid & (DD - 1);
    int rest = gid >> 11;     // 0..63
    int b = rest & 3;
    int c = rest >> 2;        // 0..15
    const u32* p = pair + ((size_t)(b * TT + c * CLEN)) * DD + e;
    float gsum = 0.f, h = 0.f;
#pragma unroll 4
    for (int t = 0; t < CLEN; ++t) {
        u32 v = *p; p += DD;
        float gf = __uint_as_float(v << 16);
        float xbv = __uint_as_float(v & 0xFFFF0000u);
        gsum += gf;
        h = fmaf(__expf(-gf), h, xbv);
    }
    int idx = ((b * NCHUNK + c) << 11) | e;
    aggG[idx] = gsum;
    aggB[idx] = h;
}

__global__ __launch_bounds__(256) void scanB(const float* __restrict__ aggG,
                                             const float* __restrict__ aggB,
                                             float* __restrict__ carry) {
    int gid = blockIdx.x * 256 + threadIdx.x;   // 8192
    int e = gid & (DD - 1);
    int b = gid >> 11;
    float h = 0.f;
#pragma unroll
    for (int c = 0; c < NCHUNK; ++c) {
        int idx = ((b * NCHUNK + c) << 11) | e;
        carry[idx] = h;
        h = fmaf(__expf(-aggG[idx]), h, aggB[idx]);
    }
}

__global__ __launch_bounds__(256) void scanC(const u32* __restrict__ pair,
                                             const float* __restrict__ carry,
                                             float* __restrict__ out) {
    int gid = blockIdx.x * 256 + threadIdx.x;   // 131072
    int e = gid & (DD - 1);
    int rest = gid >> 11;
    int b = rest & 3;
    int c = rest >> 2;
    const u32* p = pair + ((size_t)(b * TT + c * CLEN)) * DD + e;
    float* o = out + ((size_t)(b * TT + c * CLEN)) * DD + e;
    float h = carry[((b * NCHUNK + c) << 11) | e];
#pragma unroll 4
    for (int t = 0; t < CLEN; ++t) {
        u32 v = *p; p += DD;
        float gf = __uint_as_float(v << 16);
        float xbv = __uint_as_float(v & 0xFFFF0000u);
        h = fmaf(__expf(-gf), h, xbv);
        *o = h; o += DD;
    }
}

extern "C" void kernel_launch(void* const* d_in, const int* in_sizes, int n_in,
                              void* d_out, int out_size, void* d_ws, size_t ws_size,
                              hipStream_t stream) {
    const float* x      = (const float*)d_in[0];
    const float* W_in   = (const float*)d_in[1];
    const float* b_in   = (const float*)d_in[2];
    const float* W_gate = (const float*)d_in[3];
    const float* b_gate = (const float*)d_in[4];
    const float* lam    = (const float*)d_in[5];
    float* out = (float*)d_out;

    char* ws = (char*)d_ws;
    u16* xb   = (u16*)(ws);                  // 67,108,864 B
    u16* wib  = (u16*)(ws + 67108864);       //  8,388,608 B
    u16* wgb  = (u16*)(ws + 75497472);       //  8,388,608 B
    u32* pair = (u32*)(ws + 83886080);       // 134,217,728 B
    float* aggG  = (float*)(ws + 218103808); // 524,288 B
    float* aggB  = (float*)(ws + 218628096); // 524,288 B
    float* carry = (float*)(ws + 219152384); // 524,288 B

    cvt_kernel<<<16384, 256, 0, stream>>>(x, xb, MM * KK / 8);
    cvt_kernel<<<2048, 256, 0, stream>>>(W_in, wib, DD * KK / 8);
    cvt_kernel<<<2048, 256, 0, stream>>>(W_gate, wgb, DD * KK / 8);
    gemm_dual8<<<(MM / BMg) * (DD / BNg), 512, 0, stream>>>(xb, wib, wgb, b_in, b_gate, lam, pair);
    scanA<<<BB * DD * NCHUNK / 256, 256, 0, stream>>>(pair, aggG, aggB);
    scanB<<<BB * DD / 256, 256, 0, stream>>>(aggG, aggB, carry);
    scanC<<<BB * DD * NCHUNK / 256, 256, 0, stream>>>(pair, carry, out);
}